// Round 7
// baseline (70301.501 us; speedup 1.0000x reference)
//
#include <hip/hip_runtime.h>
#include <hip/hip_bf16.h>
#include <math.h>

typedef __attribute__((ext_vector_type(8))) short bf16x8;
typedef __attribute__((ext_vector_type(4))) float f32x4;

// ---- workspace byte offsets ----
#define B_X2    0u            // 512*32*256 bf16  = 8388608
#define B_PM    8388608u      // 32*256*128 f32   = 4194304
#define B_WSA   12582912u     // 4096*1792 bf16   = 14680064
#define B_WSD   27262976u     // 4096*2560 bf16   = 20971520
#define B_AHB0  48234496u     // 32*1024 bf16
#define B_AHB1  48300032u
#define B_DHB0  48365568u
#define B_DHB1  48431104u
#define B_CTXB0 48496640u     // 32*512 bf16
#define B_AC    48529408u     // 32*1024 f32
#define B_DC    48660480u
#define B_AWC   48791552u     // 32*256 f32
#define B_ZERO_START 48234496u
#define B_ZERO_BYTES 589824u
#define B_AHF   48824320u     // 32*1024 f32
#define B_DHF0  48955392u     // 32*1024 f32
#define B_CTXF0 49086464u     // 32*512 f32
#define B_CTXF1 49152000u     // 32*512 f32
#define B_DHF1  49217536u     // 32*1024 f32
#define B_LPM   49348608u     // 32*256*128 f32 = 4194304
#define B_AHB2  53542912u     // 32*1024 bf16 (3rd ah slot)
#define B_CTXF2 53608448u     // 32*512 f32  (3rd ctxf slot)
#define B_CTXB1 53673984u     // 32*512 bf16 (2nd ctxb slot)
#define B_CNT   53706752u     // barrier counter
#define B_ZERO2_START 53542912u
#define B_ZERO2_BYTES 163968u

// ---- output offsets (floats) ----
#define OUT_MEL   0u
#define OUT_GATE  1310720u
#define OUT_ALIGN 1327104u

// ---- persistent-kernel LDS layout ----
#define LWD_OFF   0         // 81920  : lstmD weight tile
#define LWA_OFF   81920     // 57344  : lstmA weight tile
#define WORK_OFF  139264    // 22784  : working overlay
#define LDS_BYTES 162048

__device__ __forceinline__ float sigf(float x) { return 1.f / (1.f + expf(-x)); }
__device__ __forceinline__ float ftanh(float x) {
    float t = exp2f(x * 2.885390081777927f);
    return 1.f - 2.f * __builtin_amdgcn_rcpf(t + 1.f);
}

#define HOLD(s, b0, b1) ((((s) & 1)) ? (b0) : (b1))

// ---- grid barrier: monotonic counter, 1 atomic/block, relaxed spin ----
__device__ __forceinline__ void gbar(int* cnt, int target) {
    __syncthreads();
    if (threadIdx.x == 0) {
        __builtin_amdgcn_fence(__ATOMIC_RELEASE, "agent");
        __hip_atomic_fetch_add(cnt, 1, __ATOMIC_RELAXED, __HIP_MEMORY_SCOPE_AGENT);
        while (__hip_atomic_load(cnt, __ATOMIC_RELAXED, __HIP_MEMORY_SCOPE_AGENT) < target)
            __builtin_amdgcn_s_sleep(16);
        __builtin_amdgcn_fence(__ATOMIC_ACQUIRE, "agent");
    }
    __syncthreads();
}

// ============================================================
// Prenet for all timesteps -> bf16 x2[t][b][256]
// ============================================================
__global__ __launch_bounds__(256) void prenet_kernel(
    const float* __restrict__ dec_in,
    const float* __restrict__ w1,
    const float* __restrict__ w2,
    __hip_bfloat16* __restrict__ x2)
{
    int b  = blockIdx.x & 31;
    int t0 = (blockIdx.x >> 5) * 16;
    __shared__ float xin[16][80];
    __shared__ float h1[16][257];

    for (int i = threadIdx.x; i < 16 * 80; i += 256) {
        int tt = i / 80, m = i - tt * 80;
        int t = t0 + tt;
        xin[tt][m] = (t == 0) ? 0.f
                   : dec_in[(size_t)b * 80 * 512 + (size_t)m * 512 + (t - 1)];
    }
    __syncthreads();
    for (int i = threadIdx.x; i < 16 * 256; i += 256) {
        int tt = i >> 8, p = i & 255;
        const float* wr = w1 + p * 80;
        float s = 0.f;
        for (int m = 0; m < 80; ++m) s += xin[tt][m] * wr[m];
        h1[tt][p] = fmaxf(s, 0.f);
    }
    __syncthreads();
    for (int i = threadIdx.x; i < 16 * 256; i += 256) {
        int tt = i >> 8, q = i & 255;
        const float* wr = w2 + q * 256;
        float s = 0.f;
        for (int p = 0; p < 256; ++p) s += h1[tt][p] * wr[p];
        int t = t0 + tt;
        x2[(size_t)t * (32 * 256) + b * 256 + q] = __float2bfloat16(fmaxf(s, 0.f));
    }
}

// ============================================================
// processed_memory (f32)
// ============================================================
__global__ __launch_bounds__(128) void pm_kernel(
    const float* __restrict__ memory,
    const float* __restrict__ wm,
    float* __restrict__ pm)
{
    int b = blockIdx.y, tt0 = blockIdx.x * 16;
    __shared__ float ms[16][513];
    for (int i = threadIdx.x; i < 16 * 512; i += 128) {
        int tt = i >> 9, e = i & 511;
        ms[tt][e] = memory[(size_t)b * 131072 + (size_t)(tt0 + tt) * 512 + e];
    }
    __syncthreads();
    int d = threadIdx.x;
    float acc[16];
#pragma unroll
    for (int i = 0; i < 16; ++i) acc[i] = 0.f;
    const float* wr = wm + d * 512;
    for (int e = 0; e < 512; ++e) {
        float w = wr[e];
#pragma unroll
        for (int ttl = 0; ttl < 16; ++ttl) acc[ttl] += w * ms[ttl][e];
    }
    for (int ttl = 0; ttl < 16; ++ttl)
        pm[(size_t)b * 32768 + (size_t)(tt0 + ttl) * 128 + d] = acc[ttl];
}

// ============================================================
// Weight swizzle (unchanged)
// ============================================================
__global__ __launch_bounds__(256) void swizzle_kernel(
    const float* __restrict__ wih, int Kih,
    const float* __restrict__ whh, int Khh,
    __hip_bfloat16* __restrict__ out, int K)
{
    int idx = blockIdx.x * 256 + threadIdx.x;
    int lane = idx & 63;
    int tk = idx >> 6;
    int KB = K >> 5;
    int nt = tk / KB, kb = tk - nt * KB;
    int c = lane & 15;
    int n = (c >> 2) * 1024 + nt * 4 + (c & 3);
    int k = kb * 32 + ((lane >> 4) << 3);
    const float* src; int kk;
    if (k < Kih) { src = wih + (size_t)n * Kih; kk = k; }
    else         { src = whh + (size_t)n * Khh; kk = k - Kih; }
    __hip_bfloat16* op = out + (size_t)idx * 8;
#pragma unroll
    for (int j = 0; j < 8; ++j) op[j] = __float2bfloat16(src[kk + j]);
}

// ============================================================
// LSTM gates GEMM tile; weights from LDS (per-block tile).
// S1F: seg1 from f32 buffer (in-register bf16 round, bit-identical).
// ============================================================
template<int K, int S0, int S1, int S0STR, int S1STR, int S2STR, bool S1F>
__device__ __forceinline__ void lstm_tile_lds(
    char* work, const __hip_bfloat16* lw, int nt,
    const __hip_bfloat16* seg0,
    const __hip_bfloat16* seg1b,
    const float* seg1f,
    const __hip_bfloat16* seg2,
    const float* bias,
    float* c_state,
    float* h_f32,
    __hip_bfloat16* h_bf16)
{
    constexpr int NCH = K / 256;

    float (*red)[2][4][64] = (float(*)[2][4][64])work;
    float (*gsum)[17]      = (float(*)[17])(work + 16384);

    int tid  = threadIdx.x;
    int lane = tid & 63;
    int w    = tid >> 6;
    int r0   = lane & 15;
    int kq   = (lane >> 4) << 3;

    const __hip_bfloat16* wp = lw + (((size_t)w * NCH) * 64 + lane) * 8;
    f32x4 acc0 = {0.f, 0.f, 0.f, 0.f};
    f32x4 acc1 = {0.f, 0.f, 0.f, 0.f};
    int k0 = w * (K / 8);

#pragma unroll
    for (int i = 0; i < NCH; ++i) {
        int kc = k0 + i * 32;
        bf16x8 a0, a1;
        if (S1F && kc >= S0 && kc < S0 + S1) {
            int ko = (kc - S0) + kq;
            const float* cp0 = seg1f + (size_t)r0 * S1STR + ko;
            const float* cp1 = seg1f + (size_t)(r0 + 16) * S1STR + ko;
            float4 x0 = *(const float4*)cp0, x1 = *(const float4*)(cp0 + 4);
            float4 y0 = *(const float4*)cp1, y1 = *(const float4*)(cp1 + 4);
            union { bf16x8 vv; __hip_bfloat16 h[8]; } u0, u1;
            u0.h[0] = __float2bfloat16(x0.x); u0.h[1] = __float2bfloat16(x0.y);
            u0.h[2] = __float2bfloat16(x0.z); u0.h[3] = __float2bfloat16(x0.w);
            u0.h[4] = __float2bfloat16(x1.x); u0.h[5] = __float2bfloat16(x1.y);
            u0.h[6] = __float2bfloat16(x1.z); u0.h[7] = __float2bfloat16(x1.w);
            u1.h[0] = __float2bfloat16(y0.x); u1.h[1] = __float2bfloat16(y0.y);
            u1.h[2] = __float2bfloat16(y0.z); u1.h[3] = __float2bfloat16(y0.w);
            u1.h[4] = __float2bfloat16(y1.x); u1.h[5] = __float2bfloat16(y1.y);
            u1.h[6] = __float2bfloat16(y1.z); u1.h[7] = __float2bfloat16(y1.w);
            a0 = u0.vv; a1 = u1.vv;
        } else {
            const __hip_bfloat16* sp; int sstr, off;
            if (kc < S0)           { sp = seg0;  sstr = S0STR; off = kc; }
            else if (kc < S0 + S1) { sp = seg1b; sstr = S1STR; off = kc - S0; }
            else                   { sp = seg2;  sstr = S2STR; off = kc - S0 - S1; }
            int ko = off + kq;
            a0 = *(const bf16x8*)(sp + (size_t)r0 * sstr + ko);
            a1 = *(const bf16x8*)(sp + (size_t)(r0 + 16) * sstr + ko);
        }
        bf16x8 bb = *(const bf16x8*)(wp + (size_t)i * 512);
        acc0 = __builtin_amdgcn_mfma_f32_16x16x32_bf16(a0, bb, acc0, 0, 0, 0);
        acc1 = __builtin_amdgcn_mfma_f32_16x16x32_bf16(a1, bb, acc1, 0, 0, 0);
    }

#pragma unroll
    for (int r = 0; r < 4; ++r) {
        red[w][0][r][lane] = acc0[r];
        red[w][1][r][lane] = acc1[r];
    }
    __syncthreads();

    {
        int b = tid >> 4, c = tid & 15;
        int mt = b >> 4, bm = b & 15;
        int lidx = ((bm >> 2) << 4) + c, rg = bm & 3;
        float s = 0.f;
#pragma unroll
        for (int ks = 0; ks < 8; ++ks) s += red[ks][mt][rg][lidx];
        gsum[b][c] = s;
    }
    __syncthreads();

    if (tid < 128) {
        int b = tid & 31, jl = tid >> 5;
        int j = nt * 4 + jl;
        float gi = gsum[b][jl]      + bias[j];
        float gf = gsum[b][4 + jl]  + bias[1024 + j];
        float gg = gsum[b][8 + jl]  + bias[2048 + j];
        float go = gsum[b][12 + jl] + bias[3072 + j];
        float cv = c_state[b * 1024 + j];
        float c2 = sigf(gf) * cv + sigf(gi) * tanhf(gg);
        float h2 = sigf(go) * tanhf(c2);
        c_state[b * 1024 + j] = c2;
        h_f32[b * 1024 + j]   = h2;
        h_bf16[b * 1024 + j]  = __float2bfloat16(h2);
    }
}

// ============================================================
// Persistent kernel: 256 blocks x 512 threads, 1 block/CU.
// LDS: lstmD tile (80K) + lstmA tile (56K) cached once + 22K work.
// Per iteration t:
//   P: attn(t)[0-31] | lstmD(t-1)[32-255] | proj(t-2)[32-95]
//   Q: lstmA(t+1)[all] | lstmD(t-1) tiles 0-31 [0-31] | lpm(t+1)[224-255]
// ============================================================
__global__ __launch_bounds__(512, 1) void persist_kernel(
    const float* __restrict__ memory,
    const int*   __restrict__ mlen,
    const float* __restrict__ wq,
    const float* __restrict__ v,
    const float* __restrict__ lconv,
    const float* __restrict__ ldense,
    const float* __restrict__ pm,
    const __hip_bfloat16* __restrict__ x2b,
    const __hip_bfloat16* __restrict__ wswA,
    const __hip_bfloat16* __restrict__ wswD,
    const float* __restrict__ a_b,
    const float* __restrict__ d_b,
    float* __restrict__ ac,
    float* __restrict__ dc,
    float* __restrict__ ahf,
    __hip_bfloat16* __restrict__ ahb0,
    __hip_bfloat16* __restrict__ ahb1,
    __hip_bfloat16* __restrict__ ahb2,
    __hip_bfloat16* __restrict__ dhb0,
    __hip_bfloat16* __restrict__ dhb1,
    __hip_bfloat16* __restrict__ ctxb0,
    __hip_bfloat16* __restrict__ ctxb1,
    float* __restrict__ ctxf0,
    float* __restrict__ ctxf1,
    float* __restrict__ ctxf2,
    float* __restrict__ dhf0,
    float* __restrict__ dhf1,
    float* __restrict__ awc,
    float* __restrict__ align_out,
    float* __restrict__ lpmbuf,
    const float* __restrict__ proj_w,
    const float* __restrict__ proj_b,
    const float* __restrict__ gate_w,
    const float* __restrict__ gate_b,
    float* __restrict__ out_mel,
    float* __restrict__ out_gate,
    int* __restrict__ cnt)
{
    extern __shared__ char smem[];
    __hip_bfloat16* lwD = (__hip_bfloat16*)(smem + LWD_OFF);
    __hip_bfloat16* lwA = (__hip_bfloat16*)(smem + LWA_OFF);
    char* work = smem + WORK_OFF;

    int blk = blockIdx.x, tid = threadIdx.x;

    // slot helpers
    auto AH = [&](int s) -> __hip_bfloat16* {
        int m = s % 3; if (m < 0) m += 3;
        return m == 0 ? ahb0 : (m == 1 ? ahb1 : ahb2);
    };
    auto CTXF = [&](int s) -> float* {
        int m = s % 3; if (m < 0) m += 3;
        return m == 0 ? ctxf0 : (m == 1 ? ctxf1 : ctxf2);
    };
    auto runLstmD = [&](int s) {
        lstm_tile_lds<2560, 1024, 512, 1024, 512, 1024, true>(
            work, lwD, blk,
            AH(s), nullptr, CTXF(s), HOLD(s - 1, dhb0, dhb1),
            d_b, dc, HOLD(s, dhf1, dhf0), HOLD(s, dhb0, dhb1));
    };

    // ---- preload weight tiles into LDS (once) ----
    {
        const float4* gD = (const float4*)(wswD + (size_t)blk * 40960);
        float4* sD = (float4*)lwD;
        for (int i = tid; i < 5120; i += 512) sD[i] = gD[i];
        const float4* gA = (const float4*)(wswA + (size_t)blk * 28672);
        float4* sA = (float4*)lwA;
        for (int i = tid; i < 3584; i += 512) sA[i] = gA[i];
    }
    __syncthreads();

    int round = 0;
    for (int t = -1; t <= 513; ++t) {
        // ================= PHASE P =================
        if (blk >= 32) {
            if (t >= 1 && t <= 512) runLstmD(t - 1);
            if (blk < 96 && t >= 2) {
                __syncthreads();
                // ---- proj(t-2): 64 blocks, 2 per batch ----
                int pb = blk - 32;
                int b = pb >> 1, half = pb & 1;
                int tp = t - 2;
                const float* dh = HOLD(tp, dhf1, dhf0);
                const float* cx = CTXF(tp);
                float* pi = (float*)work;
                for (int i = tid; i < 1024; i += 512) pi[i] = dh[b * 1024 + i];
                if (tid < 512) pi[1024 + tid] = cx[b * 512 + tid];
                __syncthreads();
                int w = tid >> 6, lane = tid & 63;
                int nOut = half ? 41 : 40;
                for (int o = w; o < nOut; o += 8) {
                    bool isGate = (half && o == 40);
                    int m = half * 40 + o;
                    const float* wr = isGate ? gate_w : (proj_w + (size_t)m * 1536);
                    float s = 0.f;
#pragma unroll
                    for (int c = 0; c < 6; ++c) {
                        float4 wv = *(const float4*)(wr + c * 256 + lane * 4);
                        const float* pp = pi + c * 256 + lane * 4;
                        s += wv.x * pp[0] + wv.y * pp[1] + wv.z * pp[2] + wv.w * pp[3];
                    }
#pragma unroll
                    for (int mm = 32; mm >= 1; mm >>= 1) s += __shfl_xor(s, mm);
                    if (lane == 0) {
                        if (isGate) out_gate[b * 512 + tp] = s + gate_b[0];
                        else out_mel[(size_t)b * (80 * 512) + (size_t)m * 512 + tp]
                                = s + proj_b[m];
                    }
                }
            }
        } else if (t >= 0 && t <= 511) {
            // ---- attention(t), blocks 0-31, 512 threads ----
            int b = blk;
            float* red   = (float*)work;            // 2048 B
            float* pq_s  = (float*)(work + 2048);   // 512 B
            float* v_s   = (float*)(work + 2560);   // 512 B
            float* wgt_s = (float*)(work + 3072);   // 1024 B

            int len = mlen[b];

            if (tid < 128) v_s[tid] = v[tid];
            {
                int d = tid >> 2, p = tid & 3;
                const float4* wr = (const float4*)(wq + (size_t)d * 1024 + p * 256);
                const float4* hr = (const float4*)(ahf + b * 1024 + p * 256);
                float s0 = 0.f, s1 = 0.f, s2 = 0.f, s3 = 0.f;
#pragma unroll
                for (int k = 0; k < 64; k += 4) {
                    float4 a0 = wr[k],     h0 = hr[k];
                    float4 a1 = wr[k + 1], h1 = hr[k + 1];
                    float4 a2 = wr[k + 2], h2 = hr[k + 2];
                    float4 a3 = wr[k + 3], h3 = hr[k + 3];
                    s0 += a0.x * h0.x + a0.y * h0.y + a0.z * h0.z + a0.w * h0.w;
                    s1 += a1.x * h1.x + a1.y * h1.y + a1.z * h1.z + a1.w * h1.w;
                    s2 += a2.x * h2.x + a2.y * h2.y + a2.z * h2.z + a2.w * h2.w;
                    s3 += a3.x * h3.x + a3.y * h3.y + a3.z * h3.z + a3.w * h3.w;
                }
                red[tid] = (s0 + s1) + (s2 + s3);
            }
            __syncthreads();

            if (tid < 128)
                pq_s[tid] = red[tid * 4] + red[tid * 4 + 1]
                          + red[tid * 4 + 2] + red[tid * 4 + 3];
            __syncthreads();

            float pe = 0.f;
            {
                int ttc = tid >> 1, dg = tid & 1;
                const float4* lp4 = (const float4*)(lpmbuf + ((size_t)b << 15) + (size_t)ttc * 128 + dg * 64);
                const float4* pq4 = (const float4*)(pq_s + dg * 64);
                const float4* v4  = (const float4*)(v_s + dg * 64);
#pragma unroll
                for (int j = 0; j < 16; ++j) {
                    float4 x = lp4[j], pq = pq4[j], vv = v4[j];
                    pe += ftanh(x.x + pq.x) * vv.x + ftanh(x.y + pq.y) * vv.y
                        + ftanh(x.z + pq.z) * vv.z + ftanh(x.w + pq.w) * vv.w;
                }
            }
            __syncthreads();
            red[tid] = pe;
            __syncthreads();

            if (tid < 64) {
                float ev[4];
                float mx = -1e30f;
#pragma unroll
                for (int r = 0; r < 4; ++r) {
                    int tt = tid * 4 + r;
                    float e = red[tt * 2] + red[tt * 2 + 1];
                    ev[r] = (tt < len) ? e : -1e9f;
                    mx = fmaxf(mx, ev[r]);
                }
#pragma unroll
                for (int mm = 32; mm >= 1; mm >>= 1) mx = fmaxf(mx, __shfl_xor(mx, mm));
                float sum = 0.f;
#pragma unroll
                for (int r = 0; r < 4; ++r) {
                    ev[r] = exp2f((ev[r] - mx) * 1.4426950408889634f);
                    sum += ev[r];
                }
#pragma unroll
                for (int mm = 32; mm >= 1; mm >>= 1) sum += __shfl_xor(sum, mm);
                float winv = __builtin_amdgcn_rcpf(sum);
#pragma unroll
                for (int r = 0; r < 4; ++r) {
                    int tt = tid * 4 + r;
                    float wg = ev[r] * winv;
                    wgt_s[tt] = wg;
                    align_out[(size_t)b * 131072 + (size_t)t * 256 + tt] = wg;
                    awc[b * 256 + tt] += wg;
                }
            }
            __syncthreads();

            {
                int e = tid;
                const float* mr = memory + (size_t)b * 131072 + e;
                float s0 = 0.f, s1 = 0.f, s2 = 0.f, s3 = 0.f;
                float s4 = 0.f, s5 = 0.f, s6 = 0.f, s7 = 0.f;
                for (int tt = 0; tt < 256; tt += 8) {
                    s0 = fmaf(wgt_s[tt],     mr[(size_t)tt * 512],       s0);
                    s1 = fmaf(wgt_s[tt + 1], mr[(size_t)(tt + 1) * 512], s1);
                    s2 = fmaf(wgt_s[tt + 2], mr[(size_t)(tt + 2) * 512], s2);
                    s3 = fmaf(wgt_s[tt + 3], mr[(size_t)(tt + 3) * 512], s3);
                    s4 = fmaf(wgt_s[tt + 4], mr[(size_t)(tt + 4) * 512], s4);
                    s5 = fmaf(wgt_s[tt + 5], mr[(size_t)(tt + 5) * 512], s5);
                    s6 = fmaf(wgt_s[tt + 6], mr[(size_t)(tt + 6) * 512], s6);
                    s7 = fmaf(wgt_s[tt + 7], mr[(size_t)(tt + 7) * 512], s7);
                }
                float cv = ((s0 + s1) + (s2 + s3)) + ((s4 + s5) + (s6 + s7));
                CTXF(t)[b * 512 + e] = cv;
                __hip_bfloat16* cb = HOLD(t, ctxb0, ctxb1);
                cb[b * 512 + e] = __float2bfloat16(cv);
            }
        }
        ++round; gbar(cnt, round * 256);

        // ================= PHASE Q =================
        if (t <= 510) {
            int s2 = t + 1;
            lstm_tile_lds<1792, 256, 512, 256, 512, 1024, false>(
                work, lwA, blk,
                x2b + (size_t)s2 * 8192, HOLD(t, ctxb0, ctxb1), nullptr, AH(t),
                a_b, ac, ahf, AH(s2));
        }
        if (blk < 32) {
            if (t >= 1 && t <= 512) {
                __syncthreads();
                runLstmD(t - 1);        // deferred tiles 0-31
            }
        } else if (blk >= 224 && t <= 510) {
            __syncthreads();
            // ---- lpm(t+1): conv + dense + pm ----
            int b = blk - 224;
            __hip_bfloat16 (*locb)[40] = (__hip_bfloat16(*)[40])work;
            float* aw_s  = (float*)(work + 20480);
            float* awc_s = (float*)(work + 21632);

            if (tid < 288) {
                int tt = tid - 15;
                float a = 0.f, c = 0.f;
                if (tt >= 0 && tt < 256) {
                    a = (t >= 0) ? align_out[(size_t)b * 131072 + (size_t)t * 256 + tt] : 0.f;
                    c = awc[b * 256 + tt];
                }
                aw_s[tid] = a; awc_s[tid] = c;
            }
            __syncthreads();

            for (int it = 0; it < 2; ++it) {
                int item = tid + it * 512;
                int f = item >> 5, ttg = item & 31;
                const float* kcA = lconv + f * 62;
                const float* kcB = kcA + 31;
                float ka[31], kb_[31];
#pragma unroll
                for (int k = 0; k < 31; ++k) { ka[k] = kcA[k]; kb_[k] = kcB[k]; }
                float acc[8];
#pragma unroll
                for (int s = 0; s < 8; ++s) acc[s] = 0.f;
                int base = ttg * 8;
#pragma unroll
                for (int u = 0; u < 38; ++u) {
                    float av = aw_s[base + u];
                    float cv = awc_s[base + u];
#pragma unroll
                    for (int s = 0; s < 8; ++s) {
                        int k = u - s;
                        if (k >= 0 && k < 31) {
                            acc[s] = fmaf(ka[k], av, acc[s]);
                            acc[s] = fmaf(kb_[k], cv, acc[s]);
                        }
                    }
                }
#pragma unroll
                for (int s = 0; s < 8; ++s)
                    locb[base + s][f] = __float2bfloat16(acc[s]);
            }
            __syncthreads();

            {
                int lane = tid & 63;
                int w    = tid >> 6;
                int c    = lane & 15, q = lane >> 4;

                bf16x8 Bf[8];
#pragma unroll
                for (int tc = 0; tc < 8; ++tc) {
                    int d = tc * 16 + c;
                    const float* lp = ldense + d * 32 + q * 8;
                    float4 f0 = *(const float4*)lp;
                    float4 f1 = *(const float4*)(lp + 4);
                    union { bf16x8 vv; __hip_bfloat16 h[8]; } u;
                    u.h[0] = __float2bfloat16(f0.x); u.h[1] = __float2bfloat16(f0.y);
                    u.h[2] = __float2bfloat16(f0.z); u.h[3] = __float2bfloat16(f0.w);
                    u.h[4] = __float2bfloat16(f1.x); u.h[5] = __float2bfloat16(f1.y);
                    u.h[6] = __float2bfloat16(f1.z); u.h[7] = __float2bfloat16(f1.w);
                    Bf[tc] = u.vv;
                }
#pragma unroll
                for (int half = 0; half < 2; ++half) {
                    int mt = w * 2 + half;
                    bf16x8 Af = *(const bf16x8*)&locb[mt * 16 + c][q * 8];
                    f32x4 zero = {0.f, 0.f, 0.f, 0.f};
#pragma unroll
                    for (int tc = 0; tc < 8; ++tc) {
                        f32x4 P = __builtin_amdgcn_mfma_f32_16x16x32_bf16(Af, Bf[tc], zero, 0, 0, 0);
                        int d = tc * 16 + c;
#pragma unroll
                        for (int r = 0; r < 4; ++r) {
                            int ttp = mt * 16 + q * 4 + r;
                            size_t ix = ((size_t)b << 15) + (size_t)ttp * 128 + d;
                            lpmbuf[ix] = P[r] + pm[ix];
                        }
                    }
                }
            }
        }
        ++round; gbar(cnt, round * 256);
    }
}

// ============================================================
extern "C" void kernel_launch(void* const* d_in, const int* in_sizes, int n_in,
                              void* d_out, int out_size, void* d_ws, size_t ws_size,
                              hipStream_t stream)
{
    const float* memory   = (const float*)d_in[0];
    const float* dec_in   = (const float*)d_in[1];
    const int*   mlen     = (const int*)  d_in[2];
    const float* pw1      = (const float*)d_in[3];
    const float* pw2      = (const float*)d_in[4];
    const float* a_wih    = (const float*)d_in[5];
    const float* a_whh    = (const float*)d_in[6];
    const float* a_b      = (const float*)d_in[7];
    const float* wq       = (const float*)d_in[8];
    const float* wm       = (const float*)d_in[9];
    const float* v        = (const float*)d_in[10];
    const float* lconv    = (const float*)d_in[11];
    const float* ldense   = (const float*)d_in[12];
    const float* d_wih    = (const float*)d_in[13];
    const float* d_whh    = (const float*)d_in[14];
    const float* d_b      = (const float*)d_in[15];
    const float* proj_w   = (const float*)d_in[16];
    const float* proj_b   = (const float*)d_in[17];
    const float* gate_w   = (const float*)d_in[18];
    const float* gate_b   = (const float*)d_in[19];

    char* ws = (char*)d_ws;
    __hip_bfloat16* x2b  = (__hip_bfloat16*)(ws + B_X2);
    float*          pm   = (float*)(ws + B_PM);
    __hip_bfloat16* wswA = (__hip_bfloat16*)(ws + B_WSA);
    __hip_bfloat16* wswD = (__hip_bfloat16*)(ws + B_WSD);
    __hip_bfloat16* ahb0 = (__hip_bfloat16*)(ws + B_AHB0);
    __hip_bfloat16* ahb1 = (__hip_bfloat16*)(ws + B_AHB1);
    __hip_bfloat16* ahb2 = (__hip_bfloat16*)(ws + B_AHB2);
    __hip_bfloat16* dhb0 = (__hip_bfloat16*)(ws + B_DHB0);
    __hip_bfloat16* dhb1 = (__hip_bfloat16*)(ws + B_DHB1);
    __hip_bfloat16* ctxb0= (__hip_bfloat16*)(ws + B_CTXB0);
    __hip_bfloat16* ctxb1= (__hip_bfloat16*)(ws + B_CTXB1);
    float*          ac   = (float*)(ws + B_AC);
    float*          dc   = (float*)(ws + B_DC);
    float*          awcp = (float*)(ws + B_AWC);
    float*          ahf  = (float*)(ws + B_AHF);
    float*          dhf0 = (float*)(ws + B_DHF0);
    float*          dhf1 = (float*)(ws + B_DHF1);
    float*          ctxf0= (float*)(ws + B_CTXF0);
    float*          ctxf1= (float*)(ws + B_CTXF1);
    float*          ctxf2= (float*)(ws + B_CTXF2);
    float*          lpmb = (float*)(ws + B_LPM);
    int*            cnt  = (int*)(ws + B_CNT);

    float* out       = (float*)d_out;
    float* out_mel   = out + OUT_MEL;
    float* out_gate  = out + OUT_GATE;
    float* out_align = out + OUT_ALIGN;

    hipFuncSetAttribute((const void*)persist_kernel,
                        hipFuncAttributeMaxDynamicSharedMemorySize, LDS_BYTES);

    hipMemsetAsync(ws + B_ZERO_START, 0, B_ZERO_BYTES, stream);
    hipMemsetAsync(ws + B_ZERO2_START, 0, B_ZERO2_BYTES, stream);

    prenet_kernel<<<1024, 256, 0, stream>>>(dec_in, pw1, pw2, x2b);
    pm_kernel<<<dim3(16, 32), 128, 0, stream>>>(memory, wm, pm);
    swizzle_kernel<<<3584, 256, 0, stream>>>(a_wih, 768,  a_whh, 1024, wswA, 1792);
    swizzle_kernel<<<5120, 256, 0, stream>>>(d_wih, 1536, d_whh, 1024, wswD, 2560);

    persist_kernel<<<256, 512, LDS_BYTES, stream>>>(
        memory, mlen, wq, v, lconv, ldense, pm,
        x2b, wswA, wswD, a_b, d_b, ac, dc, ahf,
        ahb0, ahb1, ahb2, dhb0, dhb1, ctxb0, ctxb1,
        ctxf0, ctxf1, ctxf2, dhf0, dhf1,
        awcp, out_align, lpmb,
        proj_w, proj_b, gate_w, gate_b,
        out_mel, out_gate, cnt);
}

// Round 8
// 24893.172 us; speedup vs baseline: 2.8241x; 2.8241x over previous
//
#include <hip/hip_runtime.h>
#include <hip/hip_bf16.h>
#include <math.h>

typedef __attribute__((ext_vector_type(8))) short bf16x8;
typedef __attribute__((ext_vector_type(4))) float f32x4;

// ---- workspace byte offsets ----
#define B_X2    0u            // 512*32*256 bf16  = 8388608
#define B_PM    8388608u      // 32*256*128 f32   = 4194304
#define B_WSA   12582912u     // 4096*1792 bf16   = 14680064
#define B_WSD   27262976u     // 4096*2560 bf16   = 20971520
#define B_AHB0  48234496u     // 32*1024 bf16
#define B_AHB1  48300032u
#define B_DHB0  48365568u
#define B_DHB1  48431104u
#define B_CTXB  48496640u     // 32*512 bf16
#define B_AC    48529408u     // 32*1024 f32
#define B_DC    48660480u
#define B_AWC   48791552u     // 32*256 f32
#define B_ZERO_START 48234496u
#define B_ZERO_BYTES 589824u
#define B_AHF   48824320u     // 32*1024 f32
#define B_DHF0  48955392u     // 32*1024 f32
#define B_CTXF0 49086464u     // 32*512 f32
#define B_CTXF1 49152000u     // 32*512 f32
#define B_DHF1  49217536u     // 32*1024 f32
#define B_LPM   49348608u     // 32*256*128 f32 = 4194304
#define B_WQT   53542912u     // 1024*128 f32 = 524288 (wq transposed)

// ---- output offsets (floats) ----
#define OUT_MEL   0u
#define OUT_GATE  1310720u
#define OUT_ALIGN 1327104u

// ---- shared memory for Q kernel (max of role needs) ----
#define QSM_BYTES 23040
// lstm: red @0 (16384), gsum @16384 (2176)            = 18560
// lpm : locb @0 (20480), aw_s @20480, awc_s @21632    = 22784
// proj: pi @0 (6144)

__device__ __forceinline__ float sigf(float x) { return 1.f / (1.f + expf(-x)); }
__device__ __forceinline__ float ftanh(float x) {
    float t = exp2f(x * 2.885390081777927f);
    return 1.f - 2.f * __builtin_amdgcn_rcpf(t + 1.f);
}

// buffer-parity helpers: buffer holding state of step s
#define HOLD(s, b0, b1) (((s) & 1) ? (b0) : (b1))

// ============================================================
// Prenet for all timesteps -> bf16 x2[t][b][256]
// ============================================================
__global__ __launch_bounds__(256) void prenet_kernel(
    const float* __restrict__ dec_in,
    const float* __restrict__ w1,
    const float* __restrict__ w2,
    __hip_bfloat16* __restrict__ x2)
{
    int b  = blockIdx.x & 31;
    int t0 = (blockIdx.x >> 5) * 16;
    __shared__ float xin[16][80];
    __shared__ float h1[16][257];

    for (int i = threadIdx.x; i < 16 * 80; i += 256) {
        int tt = i / 80, m = i - tt * 80;
        int t = t0 + tt;
        xin[tt][m] = (t == 0) ? 0.f
                   : dec_in[(size_t)b * 80 * 512 + (size_t)m * 512 + (t - 1)];
    }
    __syncthreads();
    for (int i = threadIdx.x; i < 16 * 256; i += 256) {
        int tt = i >> 8, p = i & 255;
        const float* wr = w1 + p * 80;
        float s = 0.f;
        for (int m = 0; m < 80; ++m) s += xin[tt][m] * wr[m];
        h1[tt][p] = fmaxf(s, 0.f);
    }
    __syncthreads();
    for (int i = threadIdx.x; i < 16 * 256; i += 256) {
        int tt = i >> 8, q = i & 255;
        const float* wr = w2 + q * 256;
        float s = 0.f;
        for (int p = 0; p < 256; ++p) s += h1[tt][p] * wr[p];
        int t = t0 + tt;
        x2[(size_t)t * (32 * 256) + b * 256 + q] = __float2bfloat16(fmaxf(s, 0.f));
    }
}

// ============================================================
// processed_memory (f32)
// ============================================================
__global__ __launch_bounds__(128) void pm_kernel(
    const float* __restrict__ memory,
    const float* __restrict__ wm,
    float* __restrict__ pm)
{
    int b = blockIdx.y, tt0 = blockIdx.x * 16;
    __shared__ float ms[16][513];
    for (int i = threadIdx.x; i < 16 * 512; i += 128) {
        int tt = i >> 9, e = i & 511;
        ms[tt][e] = memory[(size_t)b * 131072 + (size_t)(tt0 + tt) * 512 + e];
    }
    __syncthreads();
    int d = threadIdx.x;
    float acc[16];
#pragma unroll
    for (int i = 0; i < 16; ++i) acc[i] = 0.f;
    const float* wr = wm + d * 512;
    for (int e = 0; e < 512; ++e) {
        float w = wr[e];
#pragma unroll
        for (int ttl = 0; ttl < 16; ++ttl) acc[ttl] += w * ms[ttl][e];
    }
    for (int ttl = 0; ttl < 16; ++ttl)
        pm[(size_t)b * 32768 + (size_t)(tt0 + ttl) * 128 + d] = acc[ttl];
}

// ============================================================
// Weight swizzle (unchanged)
// ============================================================
__global__ __launch_bounds__(256) void swizzle_kernel(
    const float* __restrict__ wih, int Kih,
    const float* __restrict__ whh, int Khh,
    __hip_bfloat16* __restrict__ out, int K)
{
    int idx = blockIdx.x * 256 + threadIdx.x;
    int lane = idx & 63;
    int tk = idx >> 6;
    int KB = K >> 5;
    int nt = tk / KB, kb = tk - nt * KB;
    int c = lane & 15;
    int n = (c >> 2) * 1024 + nt * 4 + (c & 3);
    int k = kb * 32 + ((lane >> 4) << 3);
    const float* src; int kk;
    if (k < Kih) { src = wih + (size_t)n * Kih; kk = k; }
    else         { src = whh + (size_t)n * Khh; kk = k - Kih; }
    __hip_bfloat16* op = out + (size_t)idx * 8;
#pragma unroll
    for (int j = 0; j < 8; ++j) op[j] = __float2bfloat16(src[kk + j]);
}

// ============================================================
// wq transpose: wqT[k][d] = wq[d][k]  (one-off; coalesced writes)
// ============================================================
__global__ __launch_bounds__(256) void wqt_kernel(
    const float* __restrict__ wq,    // (128, 1024)
    float* __restrict__ wqT)         // (1024, 128)
{
    int idx = blockIdx.x * 256 + threadIdx.x;   // 131072 total
    int k = idx >> 7, d = idx & 127;
    wqT[idx] = wq[(size_t)d * 1024 + k];
}

// ============================================================
// LSTM gates GEMM tile + epilogue (device fn, 512 threads, no sync flags)
// ============================================================
template<int K, int S0, int S1, int S0STR, int S1STR, int S2STR>
__device__ __forceinline__ void lstm_tile(
    char* smem, int nt,
    const __hip_bfloat16* __restrict__ seg0,
    const __hip_bfloat16* __restrict__ seg1,
    const __hip_bfloat16* __restrict__ seg2,
    const __hip_bfloat16* __restrict__ wsw,
    const float* __restrict__ bias,
    float* __restrict__ c_state,
    float* __restrict__ h_f32,
    __hip_bfloat16* __restrict__ h_bf16)
{
    constexpr int KB  = K / 32;
    constexpr int NCH = K / 256;

    float (*red)[2][4][64] = (float(*)[2][4][64])smem;
    float (*gsum)[17]      = (float(*)[17])(smem + 16384);

    int tid  = threadIdx.x;
    int lane = tid & 63;
    int w    = tid >> 6;
    int r0   = lane & 15;
    int kq   = (lane >> 4) << 3;

    const __hip_bfloat16* wp = wsw + (((size_t)nt * KB + (size_t)w * NCH) * 64 + lane) * 8;
    f32x4 acc0 = {0.f, 0.f, 0.f, 0.f};
    f32x4 acc1 = {0.f, 0.f, 0.f, 0.f};
    int k0 = w * (K / 8);

#pragma unroll
    for (int i = 0; i < NCH; ++i) {
        int kc = k0 + i * 32;
        const __hip_bfloat16* sp; int sstr, off;
        if (kc < S0)           { sp = seg0; sstr = S0STR; off = kc; }
        else if (kc < S0 + S1) { sp = seg1; sstr = S1STR; off = kc - S0; }
        else                   { sp = seg2; sstr = S2STR; off = kc - S0 - S1; }
        int ko = off + kq;
        bf16x8 a0 = *(const bf16x8*)(sp + (size_t)r0 * sstr + ko);
        bf16x8 a1 = *(const bf16x8*)(sp + (size_t)(r0 + 16) * sstr + ko);
        bf16x8 bb = *(const bf16x8*)(wp + (size_t)i * 512);
        acc0 = __builtin_amdgcn_mfma_f32_16x16x32_bf16(a0, bb, acc0, 0, 0, 0);
        acc1 = __builtin_amdgcn_mfma_f32_16x16x32_bf16(a1, bb, acc1, 0, 0, 0);
    }

#pragma unroll
    for (int r = 0; r < 4; ++r) {
        red[w][0][r][lane] = acc0[r];
        red[w][1][r][lane] = acc1[r];
    }
    __syncthreads();

    {
        int b = tid >> 4, c = tid & 15;
        int mt = b >> 4, bm = b & 15;
        int lidx = ((bm >> 2) << 4) + c, rg = bm & 3;
        float s = 0.f;
#pragma unroll
        for (int ks = 0; ks < 8; ++ks) s += red[ks][mt][rg][lidx];
        gsum[b][c] = s;
    }
    __syncthreads();

    if (tid < 128) {
        int b = tid & 31, jl = tid >> 5;
        int j = nt * 4 + jl;
        float gi = gsum[b][jl]      + bias[j];
        float gf = gsum[b][4 + jl]  + bias[1024 + j];
        float gg = gsum[b][8 + jl]  + bias[2048 + j];
        float go = gsum[b][12 + jl] + bias[3072 + j];
        float cv = c_state[b * 1024 + j];
        float c2 = sigf(gf) * cv + sigf(gi) * tanhf(gg);
        float h2 = sigf(go) * tanhf(c2);
        c_state[b * 1024 + j] = c2;
        h_f32[b * 1024 + j]   = h2;
        h_bf16[b * 1024 + j]  = __float2bfloat16(h2);
    }
}

// ============================================================
// Q kernel: all work whose inputs are ready after attn(t).
//   [0,256)   lstmD(t)
//   [256,512) lstmA(t+1)
//   [512,544) lpm(t+1) = loc_conv+dense(align(t), awc(t)) + pm
//   [544,608) proj(t-1)
// No cross-block dependencies inside the kernel.
// ============================================================
__global__ __launch_bounds__(512, 2) void qstep_kernel(
    const __hip_bfloat16* __restrict__ x2b,
    __hip_bfloat16* __restrict__ ctxb,
    __hip_bfloat16* __restrict__ ahb0, __hip_bfloat16* __restrict__ ahb1,
    __hip_bfloat16* __restrict__ dhb0, __hip_bfloat16* __restrict__ dhb1,
    const __hip_bfloat16* __restrict__ wswA,
    const __hip_bfloat16* __restrict__ wswD,
    const float* __restrict__ a_b, const float* __restrict__ d_b,
    float* __restrict__ ac, float* __restrict__ dc,
    float* __restrict__ ahf,
    float* __restrict__ dhf0, float* __restrict__ dhf1,
    const float* __restrict__ ctxf0, const float* __restrict__ ctxf1,
    const float* __restrict__ proj_w, const float* __restrict__ proj_b,
    const float* __restrict__ gate_w, const float* __restrict__ gate_b,
    float* __restrict__ out_mel, float* __restrict__ out_gate,
    const float* __restrict__ lconv, const float* __restrict__ ldense,
    const float* __restrict__ pm,
    const float* __restrict__ awc, const float* __restrict__ align_out,
    float* __restrict__ lpmbuf,
    int t)
{
    __shared__ char smem[QSM_BYTES];
    int blk = blockIdx.x;
    int tid = threadIdx.x;

    if (blk < 256) {
        // ---------------- lstmD(t) ----------------
        if (t < 0) return;
        lstm_tile<2560, 1024, 512, 1024, 512, 1024>(
            smem, blk,
            HOLD(t, ahb0, ahb1), ctxb, HOLD(t - 1, dhb0, dhb1),
            wswD, d_b, dc,
            HOLD(t, dhf1, dhf0), HOLD(t, dhb0, dhb1));
        return;
    }

    if (blk < 512) {
        // ---------------- lstmA(t+1) ----------------
        int s = t + 1;
        if (s > 511) return;
        lstm_tile<1792, 256, 512, 256, 512, 1024>(
            smem, blk - 256,
            x2b + (size_t)s * 8192, ctxb, HOLD(s - 1, ahb0, ahb1),
            wswA, a_b, ac, ahf, HOLD(s, ahb0, ahb1));
        return;
    }

    if (blk < 544) {
        // ---------------- lpm(t+1): conv + dense + pm ----------------
        if (t + 1 > 511) return;
        int b = blk - 512;
        __hip_bfloat16 (*locb)[40] = (__hip_bfloat16(*)[40])smem;
        float* aw_s  = (float*)(smem + 20480);
        float* awc_s = (float*)(smem + 21632);

        if (tid < 288) {
            int tt = tid - 15;
            float a = 0.f, c = 0.f;
            if (tt >= 0 && tt < 256) {
                a = (t >= 0) ? align_out[(size_t)b * 131072 + (size_t)t * 256 + tt] : 0.f;
                c = awc[b * 256 + tt];
            }
            aw_s[tid] = a; awc_s[tid] = c;
        }
        __syncthreads();

        for (int it = 0; it < 2; ++it) {
            int item = tid + it * 512;
            int f = item >> 5, ttg = item & 31;
            const float* kcA = lconv + f * 62;
            const float* kcB = kcA + 31;
            float ka[31], kb_[31];
#pragma unroll
            for (int k = 0; k < 31; ++k) { ka[k] = kcA[k]; kb_[k] = kcB[k]; }
            float acc[8];
#pragma unroll
            for (int s = 0; s < 8; ++s) acc[s] = 0.f;
            int base = ttg * 8;
#pragma unroll
            for (int u = 0; u < 38; ++u) {
                float av = aw_s[base + u];
                float cv = awc_s[base + u];
#pragma unroll
                for (int s = 0; s < 8; ++s) {
                    int k = u - s;
                    if (k >= 0 && k < 31) {
                        acc[s] = fmaf(ka[k], av, acc[s]);
                        acc[s] = fmaf(kb_[k], cv, acc[s]);
                    }
                }
            }
#pragma unroll
            for (int s = 0; s < 8; ++s)
                locb[base + s][f] = __float2bfloat16(acc[s]);
        }
        __syncthreads();

        // dense via MFMA; wave w covers m-tiles 2w, 2w+1; write loc+pm (f32)
        {
            int lane = tid & 63;
            int w    = tid >> 6;
            int c    = lane & 15, q = lane >> 4;

            bf16x8 Bf[8];
#pragma unroll
            for (int tc = 0; tc < 8; ++tc) {
                int d = tc * 16 + c;
                const float* lp = ldense + d * 32 + q * 8;
                float4 f0 = *(const float4*)lp;
                float4 f1 = *(const float4*)(lp + 4);
                union { bf16x8 vv; __hip_bfloat16 h[8]; } u;
                u.h[0] = __float2bfloat16(f0.x); u.h[1] = __float2bfloat16(f0.y);
                u.h[2] = __float2bfloat16(f0.z); u.h[3] = __float2bfloat16(f0.w);
                u.h[4] = __float2bfloat16(f1.x); u.h[5] = __float2bfloat16(f1.y);
                u.h[6] = __float2bfloat16(f1.z); u.h[7] = __float2bfloat16(f1.w);
                Bf[tc] = u.vv;
            }
#pragma unroll
            for (int half = 0; half < 2; ++half) {
                int mt = w * 2 + half;
                bf16x8 Af = *(const bf16x8*)&locb[mt * 16 + c][q * 8];
                f32x4 zero = {0.f, 0.f, 0.f, 0.f};
#pragma unroll
                for (int tc = 0; tc < 8; ++tc) {
                    f32x4 P = __builtin_amdgcn_mfma_f32_16x16x32_bf16(Af, Bf[tc], zero, 0, 0, 0);
                    int d = tc * 16 + c;
#pragma unroll
                    for (int r = 0; r < 4; ++r) {
                        int ttp = mt * 16 + q * 4 + r;
                        size_t ix = ((size_t)b << 15) + (size_t)ttp * 128 + d;
                        lpmbuf[ix] = P[r] + pm[ix];
                    }
                }
            }
        }
        return;
    }

    // ---------------- proj(t-1) ----------------
    {
        if (t < 1) return;
        int pb = blk - 544;
        int b = pb >> 1, half = pb & 1;
        int tp = t - 1;
        const float* dh = HOLD(tp, dhf1, dhf0);
        const float* cx = HOLD(tp, ctxf1, ctxf0);
        float* pi = (float*)smem;
        for (int i = tid; i < 1024; i += 512) pi[i] = dh[b * 1024 + i];
        if (tid < 512) pi[1024 + tid] = cx[b * 512 + tid];
        __syncthreads();
        int w = tid >> 6, lane = tid & 63;
        int nOut = half ? 41 : 40;
        for (int o = w; o < nOut; o += 8) {
            bool isGate = (half && o == 40);
            int m = half * 40 + o;
            const float* wr = isGate ? gate_w : (proj_w + (size_t)m * 1536);
            float s = 0.f;
#pragma unroll
            for (int c = 0; c < 6; ++c) {
                float4 wv = *(const float4*)(wr + c * 256 + lane * 4);
                const float* pp = pi + c * 256 + lane * 4;
                s += wv.x * pp[0] + wv.y * pp[1] + wv.z * pp[2] + wv.w * pp[3];
            }
#pragma unroll
            for (int mm = 32; mm >= 1; mm >>= 1) s += __shfl_xor(s, mm);
            if (lane == 0) {
                if (isGate) out_gate[b * 512 + tp] = s + gate_b[0];
                else out_mel[(size_t)b * (80 * 512) + (size_t)m * 512 + tp]
                        = s + proj_b[m];
            }
        }
    }
}

// ============================================================
// P kernel: slim attention. 32 blocks x 1024 threads.
// pq (coalesced via wqT) -> energies (read lpm) -> softmax -> context
// ============================================================
__global__ __launch_bounds__(1024) void attn_kernel(
    const float* __restrict__ memory,
    const int*   __restrict__ mlen,
    const float* __restrict__ wqT,       // (1024, 128)
    const float* __restrict__ v,
    const float* __restrict__ lpmbuf,
    const float* __restrict__ ahf,
    float* __restrict__ ctxf_cur,
    __hip_bfloat16* __restrict__ ctxb,
    float* __restrict__ awc,
    float* __restrict__ align_out,
    int t)
{
    int b = blockIdx.x, tid = threadIdx.x;
    __shared__ float red[1024];
    __shared__ float pq_s[128];
    __shared__ float v_s[128];
    __shared__ float wgt_s[256];

    int len = mlen[b];

    // ---- phase A: pq partials, coalesced over wqT (+ stage v) ----
    if (tid < 128) v_s[tid] = v[tid];
    {
        int p = tid >> 7, d = tid & 127;         // p: k-chunk, d: output dim
        const float* wt = wqT + (size_t)(p * 128) * 128 + d;
        const float* hh = ahf + b * 1024 + p * 128;
        float s0 = 0.f, s1 = 0.f, s2 = 0.f, s3 = 0.f;
#pragma unroll 8
        for (int kk = 0; kk < 128; kk += 4) {
            s0 = fmaf(hh[kk],     wt[(size_t)kk * 128],       s0);
            s1 = fmaf(hh[kk + 1], wt[(size_t)(kk + 1) * 128], s1);
            s2 = fmaf(hh[kk + 2], wt[(size_t)(kk + 2) * 128], s2);
            s3 = fmaf(hh[kk + 3], wt[(size_t)(kk + 3) * 128], s3);
        }
        red[tid] = (s0 + s1) + (s2 + s3);
    }
    __syncthreads();

    // ---- phase B: pq reduce (8 partials per d, stride 128) ----
    if (tid < 128) {
        float s = 0.f;
#pragma unroll
        for (int p = 0; p < 8; ++p) s += red[p * 128 + tid];
        pq_s[tid] = s;
    }
    __syncthreads();

    // ---- phase C: energy partials; thread (tt, dg) handles 32 d ----
    {
        int ttc = tid >> 2, dg = tid & 3;
        const float4* lp4 = (const float4*)(lpmbuf + ((size_t)b << 15) + (size_t)ttc * 128 + dg * 32);
        const float4* pq4 = (const float4*)(pq_s + dg * 32);
        const float4* v4  = (const float4*)(v_s + dg * 32);
        float pe = 0.f;
#pragma unroll
        for (int j = 0; j < 8; ++j) {
            float4 x = lp4[j], pq = pq4[j], vv = v4[j];
            pe += ftanh(x.x + pq.x) * vv.x + ftanh(x.y + pq.y) * vv.y
                + ftanh(x.z + pq.z) * vv.z + ftanh(x.w + pq.w) * vv.w;
        }
        __syncthreads();          // red free for reuse
        red[tid] = pe;
    }
    __syncthreads();

    // ---- phase D: single-wave softmax + align/awc writes ----
    if (tid < 64) {
        float ev[4];
        float mx = -1e30f;
#pragma unroll
        for (int r = 0; r < 4; ++r) {
            int tt = tid * 4 + r;
            float e = red[tt * 4] + red[tt * 4 + 1] + red[tt * 4 + 2] + red[tt * 4 + 3];
            ev[r] = (tt < len) ? e : -1e9f;
            mx = fmaxf(mx, ev[r]);
        }
#pragma unroll
        for (int mm = 32; mm >= 1; mm >>= 1) mx = fmaxf(mx, __shfl_xor(mx, mm));
        float sum = 0.f;
#pragma unroll
        for (int r = 0; r < 4; ++r) {
            ev[r] = exp2f((ev[r] - mx) * 1.4426950408889634f);
            sum += ev[r];
        }
#pragma unroll
        for (int mm = 32; mm >= 1; mm >>= 1) sum += __shfl_xor(sum, mm);
        float winv = __builtin_amdgcn_rcpf(sum);
#pragma unroll
        for (int r = 0; r < 4; ++r) {
            int tt = tid * 4 + r;
            float wg = ev[r] * winv;
            wgt_s[tt] = wg;
            align_out[(size_t)b * 131072 + (size_t)t * 256 + tt] = wg;
            awc[b * 256 + tt] += wg;
        }
    }
    __syncthreads();

    // ---- phase E: context (2-way tt split, 8-way ILP) ----
    {
        int ee = tid & 511, p = tid >> 9;
        const float* mr = memory + (size_t)b * 131072 + ee;
        float s0 = 0.f, s1 = 0.f, s2 = 0.f, s3 = 0.f;
        float s4 = 0.f, s5 = 0.f, s6 = 0.f, s7 = 0.f;
        int t0 = p * 128;
        for (int ttl = 0; ttl < 128; ttl += 8) {
            int tt = t0 + ttl;
            s0 = fmaf(wgt_s[tt],     mr[(size_t)tt * 512],       s0);
            s1 = fmaf(wgt_s[tt + 1], mr[(size_t)(tt + 1) * 512], s1);
            s2 = fmaf(wgt_s[tt + 2], mr[(size_t)(tt + 2) * 512], s2);
            s3 = fmaf(wgt_s[tt + 3], mr[(size_t)(tt + 3) * 512], s3);
            s4 = fmaf(wgt_s[tt + 4], mr[(size_t)(tt + 4) * 512], s4);
            s5 = fmaf(wgt_s[tt + 5], mr[(size_t)(tt + 5) * 512], s5);
            s6 = fmaf(wgt_s[tt + 6], mr[(size_t)(tt + 6) * 512], s6);
            s7 = fmaf(wgt_s[tt + 7], mr[(size_t)(tt + 7) * 512], s7);
        }
        red[p * 512 + ee] = ((s0 + s1) + (s2 + s3)) + ((s4 + s5) + (s6 + s7));
    }
    __syncthreads();
    if (tid < 512) {
        float cv = red[tid] + red[512 + tid];
        ctxf_cur[b * 512 + tid] = cv;
        ctxb[b * 512 + tid] = __float2bfloat16(cv);
    }
}

// ============================================================
// Projection + gate (f32) — final timestep only
// ============================================================
__global__ __launch_bounds__(256) void proj_kernel(
    const float* __restrict__ dh,
    const float* __restrict__ ctx,
    const float* __restrict__ proj_w,
    const float* __restrict__ proj_b,
    const float* __restrict__ gate_w,
    const float* __restrict__ gate_b,
    float* __restrict__ out_mel,
    float* __restrict__ out_gate,
    int t)
{
    int b = blockIdx.x, tid = threadIdx.x;
    __shared__ float pi[1536];
    __shared__ float red[256];
    for (int i = tid; i < 1024; i += 256) pi[i] = dh[b * 1024 + i];
    for (int i = tid; i < 512; i += 256) pi[1024 + i] = ctx[b * 512 + i];
    __syncthreads();

    float s = 0.f;
    if (tid < 240) {
        int m = tid / 3, p = tid - m * 3;
        const float* wr = proj_w + (size_t)m * 1536 + p * 512;
        const float* pr = pi + p * 512;
        for (int k = 0; k < 512; ++k) s += wr[k] * pr[k];
    } else {
        int p = tid - 240;
        const float* wr = gate_w + p * 96;
        const float* pr = pi + p * 96;
        for (int k = 0; k < 96; ++k) s += wr[k] * pr[k];
    }
    red[tid] = s;
    __syncthreads();
    if (tid < 80) {
        float m3 = red[tid * 3] + red[tid * 3 + 1] + red[tid * 3 + 2];
        out_mel[(size_t)b * (80 * 512) + (size_t)tid * 512 + t] = m3 + proj_b[tid];
    } else if (tid == 80) {
        float g = gate_b[0];
#pragma unroll
        for (int p = 0; p < 16; ++p) g += red[240 + p];
        out_gate[b * 512 + t] = g;
    }
}

// ============================================================
extern "C" void kernel_launch(void* const* d_in, const int* in_sizes, int n_in,
                              void* d_out, int out_size, void* d_ws, size_t ws_size,
                              hipStream_t stream)
{
    const float* memory   = (const float*)d_in[0];
    const float* dec_in   = (const float*)d_in[1];
    const int*   mlen     = (const int*)  d_in[2];
    const float* pw1      = (const float*)d_in[3];
    const float* pw2      = (const float*)d_in[4];
    const float* a_wih    = (const float*)d_in[5];
    const float* a_whh    = (const float*)d_in[6];
    const float* a_b      = (const float*)d_in[7];
    const float* wq       = (const float*)d_in[8];
    const float* wm       = (const float*)d_in[9];
    const float* v        = (const float*)d_in[10];
    const float* lconv    = (const float*)d_in[11];
    const float* ldense   = (const float*)d_in[12];
    const float* d_wih    = (const float*)d_in[13];
    const float* d_whh    = (const float*)d_in[14];
    const float* d_b      = (const float*)d_in[15];
    const float* proj_w   = (const float*)d_in[16];
    const float* proj_b   = (const float*)d_in[17];
    const float* gate_w   = (const float*)d_in[18];
    const float* gate_b   = (const float*)d_in[19];

    char* ws = (char*)d_ws;
    __hip_bfloat16* x2b  = (__hip_bfloat16*)(ws + B_X2);
    float*          pm   = (float*)(ws + B_PM);
    __hip_bfloat16* wswA = (__hip_bfloat16*)(ws + B_WSA);
    __hip_bfloat16* wswD = (__hip_bfloat16*)(ws + B_WSD);
    __hip_bfloat16* ahb0 = (__hip_bfloat16*)(ws + B_AHB0);
    __hip_bfloat16* ahb1 = (__hip_bfloat16*)(ws + B_AHB1);
    __hip_bfloat16* dhb0 = (__hip_bfloat16*)(ws + B_DHB0);
    __hip_bfloat16* dhb1 = (__hip_bfloat16*)(ws + B_DHB1);
    __hip_bfloat16* ctxb = (__hip_bfloat16*)(ws + B_CTXB);
    float*          ac   = (float*)(ws + B_AC);
    float*          dc   = (float*)(ws + B_DC);
    float*          awcp = (float*)(ws + B_AWC);
    float*          ahf  = (float*)(ws + B_AHF);
    float*          dhf0 = (float*)(ws + B_DHF0);
    float*          dhf1 = (float*)(ws + B_DHF1);
    float*          ctxf0= (float*)(ws + B_CTXF0);
    float*          ctxf1= (float*)(ws + B_CTXF1);
    float*          lpmb = (float*)(ws + B_LPM);
    float*          wqt  = (float*)(ws + B_WQT);

    float* out       = (float*)d_out;
    float* out_mel   = out + OUT_MEL;
    float* out_gate  = out + OUT_GATE;
    float* out_align = out + OUT_ALIGN;

    hipMemsetAsync(ws + B_ZERO_START, 0, B_ZERO_BYTES, stream);

    prenet_kernel<<<1024, 256, 0, stream>>>(dec_in, pw1, pw2, x2b);
    pm_kernel<<<dim3(16, 32), 128, 0, stream>>>(memory, wm, pm);
    swizzle_kernel<<<3584, 256, 0, stream>>>(a_wih, 768,  a_whh, 1024, wswA, 1792);
    swizzle_kernel<<<5120, 256, 0, stream>>>(d_wih, 1536, d_whh, 1024, wswD, 2560);
    wqt_kernel<<<512, 256, 0, stream>>>(wq, wqt);

    // prologue: lstmA(0) + lpm(0)   (lstmD/proj guarded out at t=-1)
    qstep_kernel<<<608, 512, 0, stream>>>(
        x2b, ctxb, ahb0, ahb1, dhb0, dhb1, wswA, wswD, a_b, d_b,
        ac, dc, ahf, dhf0, dhf1, ctxf0, ctxf1,
        proj_w, proj_b, gate_w, gate_b, out_mel, out_gate,
        lconv, ldense, pm, awcp, out_align, lpmb, -1);

    for (int t = 0; t < 512; ++t) {
        float* ctxf_cur = (t & 1) ? ctxf1 : ctxf0;

        attn_kernel<<<32, 1024, 0, stream>>>(
            memory, mlen, wqt, v, lpmb, ahf,
            ctxf_cur, ctxb, awcp, out_align, t);

        qstep_kernel<<<608, 512, 0, stream>>>(
            x2b, ctxb, ahb0, ahb1, dhb0, dhb1, wswA, wswD, a_b, d_b,
            ac, dc, ahf, dhf0, dhf1, ctxf0, ctxf1,
            proj_w, proj_b, gate_w, gate_b, out_mel, out_gate,
            lconv, ldense, pm, awcp, out_align, lpmb, t);
    }

    // final projection for t=511 (odd -> dhf1/ctxf1)
    proj_kernel<<<32, 256, 0, stream>>>(
        dhf1, ctxf1, proj_w, proj_b, gate_w, gate_b,
        out_mel, out_gate, 511);
}

// Round 9
// 22761.606 us; speedup vs baseline: 3.0886x; 1.0936x over previous
//
#include <hip/hip_runtime.h>
#include <hip/hip_bf16.h>
#include <math.h>

typedef __attribute__((ext_vector_type(8))) short bf16x8;
typedef __attribute__((ext_vector_type(4))) float f32x4;

// ---- workspace byte offsets ----
#define B_X2    0u            // 512*32*256 bf16  = 8388608
#define B_PM    8388608u      // 32*256*128 f32   = 4194304
#define B_WSA   12582912u     // 4096*1792 bf16   = 14680064
#define B_WSD   27262976u     // 4096*2560 bf16   = 20971520
#define B_AHB0  48234496u     // 32*1024 bf16
#define B_AHB1  48300032u
#define B_DHB0  48365568u
#define B_DHB1  48431104u
#define B_CTXB  48496640u     // 32*512 bf16
#define B_AC    48529408u     // 32*1024 f32
#define B_DC    48660480u
#define B_AWC   48791552u     // 32*256 f32
#define B_ZERO_START 48234496u
#define B_ZERO_BYTES 589824u
#define B_AHF   48824320u     // 32*1024 f32
#define B_DHF0  48955392u     // 32*1024 f32
#define B_CTXF0 49086464u     // 32*512 f32
#define B_CTXF1 49152000u     // 32*512 f32
#define B_DHF1  49217536u     // 32*1024 f32
#define B_LPM   49348608u     // 32*256*128 f32 = 4194304
#define B_WQT   53542912u     // 1024*128 f32 = 524288 (wq transposed)

// ---- output offsets (floats) ----
#define OUT_MEL   0u
#define OUT_GATE  1310720u
#define OUT_ALIGN 1327104u

#define PSM_BYTES 6144
// attn: red @0 (4096), pq @4096 (512), v @4608 (512), wgt @5120 (1024)
// proj: pi @0 (6144)

#define QSM_BYTES 23040
// lstm: red @0 (16384), gsum @16384 (2176)
// lpm : locb @0 (20480), aw_s @20480, awc_s @21632

__device__ __forceinline__ float sigf(float x) { return 1.f / (1.f + expf(-x)); }
__device__ __forceinline__ float ftanh(float x) {
    float t = exp2f(x * 2.885390081777927f);
    return 1.f - 2.f * __builtin_amdgcn_rcpf(t + 1.f);
}

// buffer-parity helpers: buffer holding state of step s
#define HOLD(s, b0, b1) (((s) & 1) ? (b0) : (b1))

// ============================================================
// Prenet for all timesteps -> bf16 x2[t][b][256]
// ============================================================
__global__ __launch_bounds__(256) void prenet_kernel(
    const float* __restrict__ dec_in,
    const float* __restrict__ w1,
    const float* __restrict__ w2,
    __hip_bfloat16* __restrict__ x2)
{
    int b  = blockIdx.x & 31;
    int t0 = (blockIdx.x >> 5) * 16;
    __shared__ float xin[16][80];
    __shared__ float h1[16][257];

    for (int i = threadIdx.x; i < 16 * 80; i += 256) {
        int tt = i / 80, m = i - tt * 80;
        int t = t0 + tt;
        xin[tt][m] = (t == 0) ? 0.f
                   : dec_in[(size_t)b * 80 * 512 + (size_t)m * 512 + (t - 1)];
    }
    __syncthreads();
    for (int i = threadIdx.x; i < 16 * 256; i += 256) {
        int tt = i >> 8, p = i & 255;
        const float* wr = w1 + p * 80;
        float s = 0.f;
        for (int m = 0; m < 80; ++m) s += xin[tt][m] * wr[m];
        h1[tt][p] = fmaxf(s, 0.f);
    }
    __syncthreads();
    for (int i = threadIdx.x; i < 16 * 256; i += 256) {
        int tt = i >> 8, q = i & 255;
        const float* wr = w2 + q * 256;
        float s = 0.f;
        for (int p = 0; p < 256; ++p) s += h1[tt][p] * wr[p];
        int t = t0 + tt;
        x2[(size_t)t * (32 * 256) + b * 256 + q] = __float2bfloat16(fmaxf(s, 0.f));
    }
}

// ============================================================
// processed_memory (f32)
// ============================================================
__global__ __launch_bounds__(128) void pm_kernel(
    const float* __restrict__ memory,
    const float* __restrict__ wm,
    float* __restrict__ pm)
{
    int b = blockIdx.y, tt0 = blockIdx.x * 16;
    __shared__ float ms[16][513];
    for (int i = threadIdx.x; i < 16 * 512; i += 128) {
        int tt = i >> 9, e = i & 511;
        ms[tt][e] = memory[(size_t)b * 131072 + (size_t)(tt0 + tt) * 512 + e];
    }
    __syncthreads();
    int d = threadIdx.x;
    float acc[16];
#pragma unroll
    for (int i = 0; i < 16; ++i) acc[i] = 0.f;
    const float* wr = wm + d * 512;
    for (int e = 0; e < 512; ++e) {
        float w = wr[e];
#pragma unroll
        for (int ttl = 0; ttl < 16; ++ttl) acc[ttl] += w * ms[ttl][e];
    }
    for (int ttl = 0; ttl < 16; ++ttl)
        pm[(size_t)b * 32768 + (size_t)(tt0 + ttl) * 128 + d] = acc[ttl];
}

// ============================================================
// Weight swizzle (unchanged)
// ============================================================
__global__ __launch_bounds__(256) void swizzle_kernel(
    const float* __restrict__ wih, int Kih,
    const float* __restrict__ whh, int Khh,
    __hip_bfloat16* __restrict__ out, int K)
{
    int idx = blockIdx.x * 256 + threadIdx.x;
    int lane = idx & 63;
    int tk = idx >> 6;
    int KB = K >> 5;
    int nt = tk / KB, kb = tk - nt * KB;
    int c = lane & 15;
    int n = (c >> 2) * 1024 + nt * 4 + (c & 3);
    int k = kb * 32 + ((lane >> 4) << 3);
    const float* src; int kk;
    if (k < Kih) { src = wih + (size_t)n * Kih; kk = k; }
    else         { src = whh + (size_t)n * Khh; kk = k - Kih; }
    __hip_bfloat16* op = out + (size_t)idx * 8;
#pragma unroll
    for (int j = 0; j < 8; ++j) op[j] = __float2bfloat16(src[kk + j]);
}

// ============================================================
// wq transpose: wqT[k][d] = wq[d][k]  (one-off; coalesced writes)
// ============================================================
__global__ __launch_bounds__(256) void wqt_kernel(
    const float* __restrict__ wq,    // (128, 1024)
    float* __restrict__ wqT)         // (1024, 128)
{
    int idx = blockIdx.x * 256 + threadIdx.x;   // 131072 total
    int k = idx >> 7, d = idx & 127;
    wqT[idx] = wq[(size_t)d * 1024 + k];
}

// ============================================================
// LSTM gates GEMM tile + epilogue (device fn, 512 threads)
// ============================================================
template<int K, int S0, int S1, int S0STR, int S1STR, int S2STR>
__device__ __forceinline__ void lstm_tile(
    char* smem, int nt,
    const __hip_bfloat16* __restrict__ seg0,
    const __hip_bfloat16* __restrict__ seg1,
    const __hip_bfloat16* __restrict__ seg2,
    const __hip_bfloat16* __restrict__ wsw,
    const float* __restrict__ bias,
    float* __restrict__ c_state,
    float* __restrict__ h_f32,
    __hip_bfloat16* __restrict__ h_bf16)
{
    constexpr int KB  = K / 32;
    constexpr int NCH = K / 256;

    float (*red)[2][4][64] = (float(*)[2][4][64])smem;
    float (*gsum)[17]      = (float(*)[17])(smem + 16384);

    int tid  = threadIdx.x;
    int lane = tid & 63;
    int w    = tid >> 6;
    int r0   = lane & 15;
    int kq   = (lane >> 4) << 3;

    const __hip_bfloat16* wp = wsw + (((size_t)nt * KB + (size_t)w * NCH) * 64 + lane) * 8;
    f32x4 acc0 = {0.f, 0.f, 0.f, 0.f};
    f32x4 acc1 = {0.f, 0.f, 0.f, 0.f};
    int k0 = w * (K / 8);

#pragma unroll
    for (int i = 0; i < NCH; ++i) {
        int kc = k0 + i * 32;
        const __hip_bfloat16* sp; int sstr, off;
        if (kc < S0)           { sp = seg0; sstr = S0STR; off = kc; }
        else if (kc < S0 + S1) { sp = seg1; sstr = S1STR; off = kc - S0; }
        else                   { sp = seg2; sstr = S2STR; off = kc - S0 - S1; }
        int ko = off + kq;
        bf16x8 a0 = *(const bf16x8*)(sp + (size_t)r0 * sstr + ko);
        bf16x8 a1 = *(const bf16x8*)(sp + (size_t)(r0 + 16) * sstr + ko);
        bf16x8 bb = *(const bf16x8*)(wp + (size_t)i * 512);
        acc0 = __builtin_amdgcn_mfma_f32_16x16x32_bf16(a0, bb, acc0, 0, 0, 0);
        acc1 = __builtin_amdgcn_mfma_f32_16x16x32_bf16(a1, bb, acc1, 0, 0, 0);
    }

#pragma unroll
    for (int r = 0; r < 4; ++r) {
        red[w][0][r][lane] = acc0[r];
        red[w][1][r][lane] = acc1[r];
    }
    __syncthreads();

    {
        int b = tid >> 4, c = tid & 15;
        int mt = b >> 4, bm = b & 15;
        int lidx = ((bm >> 2) << 4) + c, rg = bm & 3;
        float s = 0.f;
#pragma unroll
        for (int ks = 0; ks < 8; ++ks) s += red[ks][mt][rg][lidx];
        gsum[b][c] = s;
    }
    __syncthreads();

    if (tid < 128) {
        int b = tid & 31, jl = tid >> 5;
        int j = nt * 4 + jl;
        float gi = gsum[b][jl]      + bias[j];
        float gf = gsum[b][4 + jl]  + bias[1024 + j];
        float gg = gsum[b][8 + jl]  + bias[2048 + j];
        float go = gsum[b][12 + jl] + bias[3072 + j];
        float cv = c_state[b * 1024 + j];
        float c2 = sigf(gf) * cv + sigf(gi) * tanhf(gg);
        float h2 = sigf(go) * tanhf(c2);
        c_state[b * 1024 + j] = c2;
        h_f32[b * 1024 + j]   = h2;
        h_bf16[b * 1024 + j]  = __float2bfloat16(h2);
    }
}

// ============================================================
// P kernel (step t): attn(t) [0,32) || proj(t-1) [32,96)
// 1024 threads. proj inputs are all previous-launch data.
// ============================================================
__global__ __launch_bounds__(1024) void pstep_kernel(
    const float* __restrict__ memory,
    const int*   __restrict__ mlen,
    const float* __restrict__ wqT,       // (1024, 128)
    const float* __restrict__ v,
    const float* __restrict__ lpmbuf,
    const float* __restrict__ ahf,
    float* __restrict__ ctxf0, float* __restrict__ ctxf1,
    __hip_bfloat16* __restrict__ ctxb,
    float* __restrict__ awc,
    float* __restrict__ align_out,
    const float* __restrict__ dhf0, const float* __restrict__ dhf1,
    const float* __restrict__ proj_w, const float* __restrict__ proj_b,
    const float* __restrict__ gate_w, const float* __restrict__ gate_b,
    float* __restrict__ out_mel, float* __restrict__ out_gate,
    int t)
{
    __shared__ char smem[PSM_BYTES];
    int blk = blockIdx.x;
    int tid = threadIdx.x;

    if (blk < 32) {
        // ---------------- attention(t) ----------------
        int b = blk;
        float* red   = (float*)smem;            // 1024 f
        float* pq_s  = (float*)(smem + 4096);   // 128 f
        float* v_s   = (float*)(smem + 4608);   // 128 f
        float* wgt_s = (float*)(smem + 5120);   // 256 f

        int len = mlen[b];

        // phase A: pq partials, coalesced over wqT (+ stage v)
        if (tid < 128) v_s[tid] = v[tid];
        {
            int p = tid >> 7, d = tid & 127;     // p: k-chunk, d: output dim
            const float* wt = wqT + (size_t)(p * 128) * 128 + d;
            const float* hh = ahf + b * 1024 + p * 128;
            float s0 = 0.f, s1 = 0.f, s2 = 0.f, s3 = 0.f;
#pragma unroll 8
            for (int kk = 0; kk < 128; kk += 4) {
                s0 = fmaf(hh[kk],     wt[(size_t)kk * 128],       s0);
                s1 = fmaf(hh[kk + 1], wt[(size_t)(kk + 1) * 128], s1);
                s2 = fmaf(hh[kk + 2], wt[(size_t)(kk + 2) * 128], s2);
                s3 = fmaf(hh[kk + 3], wt[(size_t)(kk + 3) * 128], s3);
            }
            red[tid] = (s0 + s1) + (s2 + s3);
        }
        __syncthreads();

        // phase B: pq reduce (8 partials per d, stride 128)
        if (tid < 128) {
            float s = 0.f;
#pragma unroll
            for (int p = 0; p < 8; ++p) s += red[p * 128 + tid];
            pq_s[tid] = s;
        }
        __syncthreads();

        // phase C: energy partials; thread (tt, dg) handles 32 d
        {
            int ttc = tid >> 2, dg = tid & 3;
            const float4* lp4 = (const float4*)(lpmbuf + ((size_t)b << 15) + (size_t)ttc * 128 + dg * 32);
            const float4* pq4 = (const float4*)(pq_s + dg * 32);
            const float4* v4  = (const float4*)(v_s + dg * 32);
            float pe = 0.f;
#pragma unroll
            for (int j = 0; j < 8; ++j) {
                float4 x = lp4[j], pq = pq4[j], vv = v4[j];
                pe += ftanh(x.x + pq.x) * vv.x + ftanh(x.y + pq.y) * vv.y
                    + ftanh(x.z + pq.z) * vv.z + ftanh(x.w + pq.w) * vv.w;
            }
            __syncthreads();          // red free for reuse
            red[tid] = pe;
        }
        __syncthreads();

        // phase D: single-wave softmax + align/awc writes
        if (tid < 64) {
            float ev[4];
            float mx = -1e30f;
#pragma unroll
            for (int r = 0; r < 4; ++r) {
                int tt = tid * 4 + r;
                float e = red[tt * 4] + red[tt * 4 + 1] + red[tt * 4 + 2] + red[tt * 4 + 3];
                ev[r] = (tt < len) ? e : -1e9f;
                mx = fmaxf(mx, ev[r]);
            }
#pragma unroll
            for (int mm = 32; mm >= 1; mm >>= 1) mx = fmaxf(mx, __shfl_xor(mx, mm));
            float sum = 0.f;
#pragma unroll
            for (int r = 0; r < 4; ++r) {
                ev[r] = exp2f((ev[r] - mx) * 1.4426950408889634f);
                sum += ev[r];
            }
#pragma unroll
            for (int mm = 32; mm >= 1; mm >>= 1) sum += __shfl_xor(sum, mm);
            float winv = __builtin_amdgcn_rcpf(sum);
#pragma unroll
            for (int r = 0; r < 4; ++r) {
                int tt = tid * 4 + r;
                float wg = ev[r] * winv;
                wgt_s[tt] = wg;
                align_out[(size_t)b * 131072 + (size_t)t * 256 + tt] = wg;
                awc[b * 256 + tt] += wg;
            }
        }
        __syncthreads();

        // phase E: context (2-way tt split, 8-way ILP)
        {
            int ee = tid & 511, p = tid >> 9;
            const float* mr = memory + (size_t)b * 131072 + ee;
            float s0 = 0.f, s1 = 0.f, s2 = 0.f, s3 = 0.f;
            float s4 = 0.f, s5 = 0.f, s6 = 0.f, s7 = 0.f;
            int t0 = p * 128;
            for (int ttl = 0; ttl < 128; ttl += 8) {
                int tt = t0 + ttl;
                s0 = fmaf(wgt_s[tt],     mr[(size_t)tt * 512],       s0);
                s1 = fmaf(wgt_s[tt + 1], mr[(size_t)(tt + 1) * 512], s1);
                s2 = fmaf(wgt_s[tt + 2], mr[(size_t)(tt + 2) * 512], s2);
                s3 = fmaf(wgt_s[tt + 3], mr[(size_t)(tt + 3) * 512], s3);
                s4 = fmaf(wgt_s[tt + 4], mr[(size_t)(tt + 4) * 512], s4);
                s5 = fmaf(wgt_s[tt + 5], mr[(size_t)(tt + 5) * 512], s5);
                s6 = fmaf(wgt_s[tt + 6], mr[(size_t)(tt + 6) * 512], s6);
                s7 = fmaf(wgt_s[tt + 7], mr[(size_t)(tt + 7) * 512], s7);
            }
            red[p * 512 + ee] = ((s0 + s1) + (s2 + s3)) + ((s4 + s5) + (s6 + s7));
        }
        __syncthreads();
        if (tid < 512) {
            float cv = red[tid] + red[512 + tid];
            float* ctxf_cur = HOLD(t, ctxf1, ctxf0);
            ctxf_cur[b * 512 + tid] = cv;
            ctxb[b * 512 + tid] = __float2bfloat16(cv);
        }
        return;
    }

    // ---------------- proj(t-1): 64 blocks, 2 per batch ----------------
    {
        if (t < 1) return;
        int pb = blk - 32;
        int b = pb >> 1, half = pb & 1;
        int tp = t - 1;
        const float* dh = HOLD(tp, dhf1, dhf0);
        const float* cx = HOLD(tp, ctxf1, ctxf0);
        float* pi = (float*)smem;
        if (tid < 1024) pi[tid] = dh[b * 1024 + tid];
        else ;
        if (tid < 512) pi[1024 + tid] = cx[b * 512 + tid];
        __syncthreads();
        int w = tid >> 6, lane = tid & 63;       // 16 waves
        int nOut = half ? 41 : 40;
        for (int o = w; o < nOut; o += 16) {
            bool isGate = (half && o == 40);
            int m = half * 40 + o;
            const float* wr = isGate ? gate_w : (proj_w + (size_t)m * 1536);
            float s = 0.f;
#pragma unroll
            for (int c = 0; c < 6; ++c) {
                float4 wv = *(const float4*)(wr + c * 256 + lane * 4);
                const float* pp = pi + c * 256 + lane * 4;
                s += wv.x * pp[0] + wv.y * pp[1] + wv.z * pp[2] + wv.w * pp[3];
            }
#pragma unroll
            for (int mm = 32; mm >= 1; mm >>= 1) s += __shfl_xor(s, mm);
            if (lane == 0) {
                if (isGate) out_gate[b * 512 + tp] = s + gate_b[0];
                else out_mel[(size_t)b * (80 * 512) + (size_t)m * 512 + tp]
                        = s + proj_b[m];
            }
        }
    }
}

// ============================================================
// Q kernel (step t): lstmD(t) [0,256) || lstmA(t+1) [256,384)
//                    (2 n-tiles/block) || lpm(t+1) [384,416)
// 416 blocks <= 512 co-residency slots -> single occupancy round.
// ============================================================
__global__ __launch_bounds__(512, 2) void qstep_kernel(
    const __hip_bfloat16* __restrict__ x2b,
    __hip_bfloat16* __restrict__ ctxb,
    __hip_bfloat16* __restrict__ ahb0, __hip_bfloat16* __restrict__ ahb1,
    __hip_bfloat16* __restrict__ dhb0, __hip_bfloat16* __restrict__ dhb1,
    const __hip_bfloat16* __restrict__ wswA,
    const __hip_bfloat16* __restrict__ wswD,
    const float* __restrict__ a_b, const float* __restrict__ d_b,
    float* __restrict__ ac, float* __restrict__ dc,
    float* __restrict__ ahf,
    float* __restrict__ dhf0, float* __restrict__ dhf1,
    const float* __restrict__ lconv, const float* __restrict__ ldense,
    const float* __restrict__ pm,
    const float* __restrict__ awc, const float* __restrict__ align_out,
    float* __restrict__ lpmbuf,
    int t)
{
    __shared__ char smem[QSM_BYTES];
    int blk = blockIdx.x;
    int tid = threadIdx.x;

    if (blk < 256) {
        // ---------------- lstmD(t) ----------------
        if (t < 0) return;
        lstm_tile<2560, 1024, 512, 1024, 512, 1024>(
            smem, blk,
            HOLD(t, ahb0, ahb1), ctxb, HOLD(t - 1, dhb0, dhb1),
            wswD, d_b, dc,
            HOLD(t, dhf1, dhf0), HOLD(t, dhb0, dhb1));
        return;
    }

    if (blk < 384) {
        // ---------------- lstmA(t+1): 2 n-tiles per block ----------------
        int s = t + 1;
        if (s > 511) return;
        int base = (blk - 256) * 2;
#pragma unroll
        for (int h = 0; h < 2; ++h) {
            if (h) __syncthreads();
            lstm_tile<1792, 256, 512, 256, 512, 1024>(
                smem, base + h,
                x2b + (size_t)s * 8192, ctxb, HOLD(s - 1, ahb0, ahb1),
                wswA, a_b, ac, ahf, HOLD(s, ahb0, ahb1));
        }
        return;
    }

    // ---------------- lpm(t+1): conv + dense + pm ----------------
    {
        if (t + 1 > 511) return;
        int b = blk - 384;
        __hip_bfloat16 (*locb)[40] = (__hip_bfloat16(*)[40])smem;
        float* aw_s  = (float*)(smem + 20480);
        float* awc_s = (float*)(smem + 21632);

        if (tid < 288) {
            int tt = tid - 15;
            float a = 0.f, c = 0.f;
            if (tt >= 0 && tt < 256) {
                a = (t >= 0) ? align_out[(size_t)b * 131072 + (size_t)t * 256 + tt] : 0.f;
                c = awc[b * 256 + tt];
            }
            aw_s[tid] = a; awc_s[tid] = c;
        }
        __syncthreads();

        for (int it = 0; it < 2; ++it) {
            int item = tid + it * 512;
            int f = item >> 5, ttg = item & 31;
            const float* kcA = lconv + f * 62;
            const float* kcB = kcA + 31;
            float ka[31], kb_[31];
#pragma unroll
            for (int k = 0; k < 31; ++k) { ka[k] = kcA[k]; kb_[k] = kcB[k]; }
            float acc[8];
#pragma unroll
            for (int s = 0; s < 8; ++s) acc[s] = 0.f;
            int base = ttg * 8;
#pragma unroll
            for (int u = 0; u < 38; ++u) {
                float av = aw_s[base + u];
                float cv = awc_s[base + u];
#pragma unroll
                for (int s = 0; s < 8; ++s) {
                    int k = u - s;
                    if (k >= 0 && k < 31) {
                        acc[s] = fmaf(ka[k], av, acc[s]);
                        acc[s] = fmaf(kb_[k], cv, acc[s]);
                    }
                }
            }
#pragma unroll
            for (int s = 0; s < 8; ++s)
                locb[base + s][f] = __float2bfloat16(acc[s]);
        }
        __syncthreads();

        // dense via MFMA; wave w covers m-tiles 2w, 2w+1; write loc+pm (f32)
        {
            int lane = tid & 63;
            int w    = tid >> 6;
            int c    = lane & 15, q = lane >> 4;

            bf16x8 Bf[8];
#pragma unroll
            for (int tc = 0; tc < 8; ++tc) {
                int d = tc * 16 + c;
                const float* lp = ldense + d * 32 + q * 8;
                float4 f0 = *(const float4*)lp;
                float4 f1 = *(const float4*)(lp + 4);
                union { bf16x8 vv; __hip_bfloat16 h[8]; } u;
                u.h[0] = __float2bfloat16(f0.x); u.h[1] = __float2bfloat16(f0.y);
                u.h[2] = __float2bfloat16(f0.z); u.h[3] = __float2bfloat16(f0.w);
                u.h[4] = __float2bfloat16(f1.x); u.h[5] = __float2bfloat16(f1.y);
                u.h[6] = __float2bfloat16(f1.z); u.h[7] = __float2bfloat16(f1.w);
                Bf[tc] = u.vv;
            }
#pragma unroll
            for (int half = 0; half < 2; ++half) {
                int mt = w * 2 + half;
                bf16x8 Af = *(const bf16x8*)&locb[mt * 16 + c][q * 8];
                f32x4 zero = {0.f, 0.f, 0.f, 0.f};
#pragma unroll
                for (int tc = 0; tc < 8; ++tc) {
                    f32x4 P = __builtin_amdgcn_mfma_f32_16x16x32_bf16(Af, Bf[tc], zero, 0, 0, 0);
                    int d = tc * 16 + c;
#pragma unroll
                    for (int r = 0; r < 4; ++r) {
                        int ttp = mt * 16 + q * 4 + r;
                        size_t ix = ((size_t)b << 15) + (size_t)ttp * 128 + d;
                        lpmbuf[ix] = P[r] + pm[ix];
                    }
                }
            }
        }
    }
}

// ============================================================
// Projection + gate (f32) — final timestep only
// ============================================================
__global__ __launch_bounds__(256) void proj_kernel(
    const float* __restrict__ dh,
    const float* __restrict__ ctx,
    const float* __restrict__ proj_w,
    const float* __restrict__ proj_b,
    const float* __restrict__ gate_w,
    const float* __restrict__ gate_b,
    float* __restrict__ out_mel,
    float* __restrict__ out_gate,
    int t)
{
    int b = blockIdx.x, tid = threadIdx.x;
    __shared__ float pi[1536];
    __shared__ float red[256];
    for (int i = tid; i < 1024; i += 256) pi[i] = dh[b * 1024 + i];
    for (int i = tid; i < 512; i += 256) pi[1024 + i] = ctx[b * 512 + i];
    __syncthreads();

    float s = 0.f;
    if (tid < 240) {
        int m = tid / 3, p = tid - m * 3;
        const float* wr = proj_w + (size_t)m * 1536 + p * 512;
        const float* pr = pi + p * 512;
        for (int k = 0; k < 512; ++k) s += wr[k] * pr[k];
    } else {
        int p = tid - 240;
        const float* wr = gate_w + p * 96;
        const float* pr = pi + p * 96;
        for (int k = 0; k < 96; ++k) s += wr[k] * pr[k];
    }
    red[tid] = s;
    __syncthreads();
    if (tid < 80) {
        float m3 = red[tid * 3] + red[tid * 3 + 1] + red[tid * 3 + 2];
        out_mel[(size_t)b * (80 * 512) + (size_t)tid * 512 + t] = m3 + proj_b[tid];
    } else if (tid == 80) {
        float g = gate_b[0];
#pragma unroll
        for (int p = 0; p < 16; ++p) g += red[240 + p];
        out_gate[b * 512 + t] = g;
    }
}

// ============================================================
extern "C" void kernel_launch(void* const* d_in, const int* in_sizes, int n_in,
                              void* d_out, int out_size, void* d_ws, size_t ws_size,
                              hipStream_t stream)
{
    const float* memory   = (const float*)d_in[0];
    const float* dec_in   = (const float*)d_in[1];
    const int*   mlen     = (const int*)  d_in[2];
    const float* pw1      = (const float*)d_in[3];
    const float* pw2      = (const float*)d_in[4];
    const float* a_wih    = (const float*)d_in[5];
    const float* a_whh    = (const float*)d_in[6];
    const float* a_b      = (const float*)d_in[7];
    const float* wq       = (const float*)d_in[8];
    const float* wm       = (const float*)d_in[9];
    const float* v        = (const float*)d_in[10];
    const float* lconv    = (const float*)d_in[11];
    const float* ldense   = (const float*)d_in[12];
    const float* d_wih    = (const float*)d_in[13];
    const float* d_whh    = (const float*)d_in[14];
    const float* d_b      = (const float*)d_in[15];
    const float* proj_w   = (const float*)d_in[16];
    const float* proj_b   = (const float*)d_in[17];
    const float* gate_w   = (const float*)d_in[18];
    const float* gate_b   = (const float*)d_in[19];

    char* ws = (char*)d_ws;
    __hip_bfloat16* x2b  = (__hip_bfloat16*)(ws + B_X2);
    float*          pm   = (float*)(ws + B_PM);
    __hip_bfloat16* wswA = (__hip_bfloat16*)(ws + B_WSA);
    __hip_bfloat16* wswD = (__hip_bfloat16*)(ws + B_WSD);
    __hip_bfloat16* ahb0 = (__hip_bfloat16*)(ws + B_AHB0);
    __hip_bfloat16* ahb1 = (__hip_bfloat16*)(ws + B_AHB1);
    __hip_bfloat16* dhb0 = (__hip_bfloat16*)(ws + B_DHB0);
    __hip_bfloat16* dhb1 = (__hip_bfloat16*)(ws + B_DHB1);
    __hip_bfloat16* ctxb = (__hip_bfloat16*)(ws + B_CTXB);
    float*          ac   = (float*)(ws + B_AC);
    float*          dc   = (float*)(ws + B_DC);
    float*          awcp = (float*)(ws + B_AWC);
    float*          ahf  = (float*)(ws + B_AHF);
    float*          dhf0 = (float*)(ws + B_DHF0);
    float*          dhf1 = (float*)(ws + B_DHF1);
    float*          ctxf0= (float*)(ws + B_CTXF0);
    float*          ctxf1= (float*)(ws + B_CTXF1);
    float*          lpmb = (float*)(ws + B_LPM);
    float*          wqt  = (float*)(ws + B_WQT);

    float* out       = (float*)d_out;
    float* out_mel   = out + OUT_MEL;
    float* out_gate  = out + OUT_GATE;
    float* out_align = out + OUT_ALIGN;

    hipMemsetAsync(ws + B_ZERO_START, 0, B_ZERO_BYTES, stream);

    prenet_kernel<<<1024, 256, 0, stream>>>(dec_in, pw1, pw2, x2b);
    pm_kernel<<<dim3(16, 32), 128, 0, stream>>>(memory, wm, pm);
    swizzle_kernel<<<3584, 256, 0, stream>>>(a_wih, 768,  a_whh, 1024, wswA, 1792);
    swizzle_kernel<<<5120, 256, 0, stream>>>(d_wih, 1536, d_whh, 1024, wswD, 2560);
    wqt_kernel<<<512, 256, 0, stream>>>(wq, wqt);

    // prologue: lstmA(0) + lpm(0)   (lstmD guarded out at t=-1)
    qstep_kernel<<<416, 512, 0, stream>>>(
        x2b, ctxb, ahb0, ahb1, dhb0, dhb1, wswA, wswD, a_b, d_b,
        ac, dc, ahf, dhf0, dhf1,
        lconv, ldense, pm, awcp, out_align, lpmb, -1);

    for (int t = 0; t < 512; ++t) {
        pstep_kernel<<<96, 1024, 0, stream>>>(
            memory, mlen, wqt, v, lpmb, ahf,
            ctxf0, ctxf1, ctxb, awcp, out_align,
            dhf0, dhf1,
            proj_w, proj_b, gate_w, gate_b, out_mel, out_gate, t);

        qstep_kernel<<<416, 512, 0, stream>>>(
            x2b, ctxb, ahb0, ahb1, dhb0, dhb1, wswA, wswD, a_b, d_b,
            ac, dc, ahf, dhf0, dhf1,
            lconv, ldense, pm, awcp, out_align, lpmb, t);
    }

    // final projection for t=511 (odd -> dhf1/ctxf1)
    proj_kernel<<<32, 256, 0, stream>>>(
        dhf1, ctxf1, proj_w, proj_b, gate_w, gate_b,
        out_mel, out_gate, 511);
}